// Round 3
// baseline (2926.114 us; speedup 1.0000x reference)
//
#include <hip/hip_runtime.h>
#include <hip/hip_bf16.h>

// Problem constants
#define BATCH   64
#define SEQ     512
#define IN0     512
#define HID     128
#define G3      384   // 3*HID
#define NLAY    5

// ---------------------------------------------------------------------------
// gemm_gx: gx[M=32768][384] = A[M][K] @ W[384][K]^T + bias[384]   (all fp32)
// Tile 64(M) x 64(N), block 256 threads, 4x4 microtile, K-step 32.
// ---------------------------------------------------------------------------
__global__ __launch_bounds__(256) void gemm_gx(const float* __restrict__ A,
                                               const float* __restrict__ W,
                                               const float* __restrict__ bias,
                                               float* __restrict__ gx,
                                               int K)
{
    __shared__ __align__(16) float As[32][68];
    __shared__ __align__(16) float Bs[32][68];

    const int row0 = blockIdx.x * 64;
    const int col0 = blockIdx.y * 64;
    const int tid  = threadIdx.x;
    const int tx   = tid & 15;
    const int ty   = tid >> 4;
    const int r    = tid >> 2;
    const int kc   = (tid & 3) * 8;

    float acc[4][4] = {};

    for (int k0 = 0; k0 < K; k0 += 32) {
        {
            const float* Ap = A + (size_t)(row0 + r) * K + k0 + kc;
            float4 a0 = *(const float4*)(Ap);
            float4 a1 = *(const float4*)(Ap + 4);
            As[kc + 0][r] = a0.x; As[kc + 1][r] = a0.y; As[kc + 2][r] = a0.z; As[kc + 3][r] = a0.w;
            As[kc + 4][r] = a1.x; As[kc + 5][r] = a1.y; As[kc + 6][r] = a1.z; As[kc + 7][r] = a1.w;
        }
        {
            const float* Wp = W + (size_t)(col0 + r) * K + k0 + kc;
            float4 b0 = *(const float4*)(Wp);
            float4 b1 = *(const float4*)(Wp + 4);
            Bs[kc + 0][r] = b0.x; Bs[kc + 1][r] = b0.y; Bs[kc + 2][r] = b0.z; Bs[kc + 3][r] = b0.w;
            Bs[kc + 4][r] = b1.x; Bs[kc + 5][r] = b1.y; Bs[kc + 6][r] = b1.z; Bs[kc + 7][r] = b1.w;
        }
        __syncthreads();

        #pragma unroll
        for (int kk = 0; kk < 32; kk++) {
            float4 a = *(const float4*)&As[kk][ty * 4];
            float4 b = *(const float4*)&Bs[kk][tx * 4];
            acc[0][0] = fmaf(a.x, b.x, acc[0][0]); acc[0][1] = fmaf(a.x, b.y, acc[0][1]);
            acc[0][2] = fmaf(a.x, b.z, acc[0][2]); acc[0][3] = fmaf(a.x, b.w, acc[0][3]);
            acc[1][0] = fmaf(a.y, b.x, acc[1][0]); acc[1][1] = fmaf(a.y, b.y, acc[1][1]);
            acc[1][2] = fmaf(a.y, b.z, acc[1][2]); acc[1][3] = fmaf(a.y, b.w, acc[1][3]);
            acc[2][0] = fmaf(a.z, b.x, acc[2][0]); acc[2][1] = fmaf(a.z, b.y, acc[2][1]);
            acc[2][2] = fmaf(a.z, b.z, acc[2][2]); acc[2][3] = fmaf(a.z, b.w, acc[2][3]);
            acc[3][0] = fmaf(a.w, b.x, acc[3][0]); acc[3][1] = fmaf(a.w, b.y, acc[3][1]);
            acc[3][2] = fmaf(a.w, b.z, acc[3][2]); acc[3][3] = fmaf(a.w, b.w, acc[3][3]);
        }
        __syncthreads();
    }

    float bb[4];
    #pragma unroll
    for (int j = 0; j < 4; j++) bb[j] = bias[col0 + tx * 4 + j];
    #pragma unroll
    for (int i = 0; i < 4; i++) {
        const int row = row0 + ty * 4 + i;
        float4 v;
        v.x = acc[i][0] + bb[0];
        v.y = acc[i][1] + bb[1];
        v.z = acc[i][2] + bb[2];
        v.w = acc[i][3] + bb[3];
        *(float4*)&gx[(size_t)row * G3 + col0 + tx * 4] = v;
    }
}

// ---------------------------------------------------------------------------
// gru_scan v2: one block per batch element, 256 threads = 4 waves.
//   lane  = tid & 63
//   half  = tid >> 7        (waves 0,1 -> k in [0,64); waves 2,3 -> k in [64,128))
//   jr    = tid & 127       matvec row-triple base: rows {jr, 128+jr, 256+jr}
//   jf    = half*64 + lane  finalize output index (redundant across wave pairs)
// h is carried in lane registers (vh); matvec broadcasts h[k] via readlane
// (VALU) instead of LDS -> removes the LDS-issue bottleneck (2304 cyc/step).
// Gate finalize is computed redundantly by all waves so each lane ends the
// step holding exactly the h element its next matvec needs: ONE barrier/step.
// ghs partials double-buffered to avoid write(t+1)/read(t) race.
// gx read directly from global per thread (3 loads issued pre-matvec,
// consumed post-barrier ~600 cyc later).
// ---------------------------------------------------------------------------
__global__ __launch_bounds__(256, 1) void gru_scan(const float* __restrict__ gx,   // [BATCH][SEQ][384]
                                                   const float* __restrict__ w_hh, // [384][128] layer slice
                                                   const float* __restrict__ b_hh, // [384] layer slice
                                                   float* __restrict__ hseq)       // [BATCH][SEQ][128]
{
    const int b    = blockIdx.x;
    const int tid  = threadIdx.x;
    const int lane = tid & 63;
    const int half = tid >> 7;
    const int jr   = tid & 127;
    const int jf   = (half << 6) | lane;
    const int ko   = half * 64;

    __shared__ float ghs[2][768];   // [buf][half*384 + gate*128 + jr]

    // ---- load this thread's 3 weight half-rows into VGPRs (192 regs) ----
    float wr[64], wz[64], wn[64];
    {
        const float4* Wr = (const float4*)(w_hh + (size_t)(jr      ) * HID + ko);
        const float4* Wz = (const float4*)(w_hh + (size_t)(jr + 128) * HID + ko);
        const float4* Wn = (const float4*)(w_hh + (size_t)(jr + 256) * HID + ko);
        #pragma unroll
        for (int q = 0; q < 16; q++) {
            float4 f;
            f = Wr[q]; wr[4*q] = f.x; wr[4*q+1] = f.y; wr[4*q+2] = f.z; wr[4*q+3] = f.w;
            f = Wz[q]; wz[4*q] = f.x; wz[4*q+1] = f.y; wz[4*q+2] = f.z; wz[4*q+3] = f.w;
            f = Wn[q]; wn[4*q] = f.x; wn[4*q+1] = f.y; wn[4*q+2] = f.z; wn[4*q+3] = f.w;
        }
    }
    const float br = half ? 0.f : b_hh[jr];
    const float bz = half ? 0.f : b_hh[jr + 128];
    const float bn = half ? 0.f : b_hh[jr + 256];

    const bool storer = (tid < 64) || (tid >= 128 && tid < 192);  // waves 0,2: unique j coverage
    const float* gxb  = gx   + (size_t)b * SEQ * G3;
    float*       hout = hseq + (size_t)b * SEQ * HID;

    float vh = 0.f;   // lane-held h[jf]

    for (int t = 0; t < SEQ; t++) {
        // issue gx loads for THIS step's finalize (arrive by the barrier)
        const float* gt = gxb + (size_t)t * G3;
        const float xr = gt[jf];
        const float xz = gt[jf + 128];
        const float xn = gt[jf + 256];

        // matvec half-dots: broadcast h[k] from lane k via readlane (VALU pipe)
        float ar = 0.f, az = 0.f, an = 0.f;
        #pragma unroll
        for (int k = 0; k < 64; k++) {
            const float hk = __int_as_float(__builtin_amdgcn_readlane(__float_as_int(vh), k));
            ar = fmaf(wr[k], hk, ar);
            az = fmaf(wz[k], hk, az);
            an = fmaf(wn[k], hk, an);
        }
        float* gb = ghs[t & 1];
        gb[half * 384 + jr      ] = ar + br;
        gb[half * 384 + jr + 128] = az + bz;
        gb[half * 384 + jr + 256] = an + bn;
        __syncthreads();

        // finalize (redundant across wave pairs; lane ends holding h[jf])
        const float ghr = gb[jf      ] + gb[384 + jf];
        const float ghz = gb[jf + 128] + gb[512 + jf];
        const float ghn = gb[jf + 256] + gb[640 + jf];
        const float rg  = 1.f / (1.f + __expf(-(xr + ghr)));
        const float zg  = 1.f / (1.f + __expf(-(xz + ghz)));
        const float pre = xn + rg * ghn;
        const float e   = __expf(-2.f * fabsf(pre));
        const float th  = copysignf((1.f - e) / (1.f + e), pre);   // tanh(pre)
        const float hnew = fmaf(zg, vh - th, th);                  // (1-z)*n + z*h
        vh = hnew;
        if (storer) hout[(size_t)t * HID + jf] = hnew;
    }
}

// ---------------------------------------------------------------------------
// fc: out[b][o] = hseq[b][T-1][:] . fc_w[o][:] + fc_b[o]
// ---------------------------------------------------------------------------
__global__ __launch_bounds__(128) void fc_kernel(const float* __restrict__ hseq,
                                                 const float* __restrict__ fc_w,
                                                 const float* __restrict__ fc_b,
                                                 float* __restrict__ out)
{
    const int b = blockIdx.x;
    const int o = threadIdx.x;
    if (o < 96) {
        const float* h = hseq + (size_t)b * (SEQ * HID) + (size_t)(SEQ - 1) * HID;
        const float* wrow = fc_w + o * HID;
        float acc = fc_b[o];
        #pragma unroll 4
        for (int k = 0; k < HID; k++) acc = fmaf(h[k], wrow[k], acc);
        out[b * 96 + o] = acc;
    }
}

// ---------------------------------------------------------------------------
extern "C" void kernel_launch(void* const* d_in, const int* in_sizes, int n_in,
                              void* d_out, int out_size, void* d_ws, size_t ws_size,
                              hipStream_t stream)
{
    const float* x         = (const float*)d_in[0]; // [64][512][512]
    const float* w_ih0     = (const float*)d_in[1]; // [384][512]
    const float* w_ih_rest = (const float*)d_in[2]; // [4][384][128]
    const float* w_hh      = (const float*)d_in[3]; // [5][384][128]
    const float* b_ih      = (const float*)d_in[4]; // [5][384]
    const float* b_hh      = (const float*)d_in[5]; // [5][384]
    const float* fc_w      = (const float*)d_in[6]; // [96][128]
    const float* fc_b      = (const float*)d_in[7]; // [96]
    float* out = (float*)d_out;                     // [64][96]

    float* gxbuf = (float*)d_ws;                    // 32768*384 fp32 = 50.3 MB
    float* hseq  = gxbuf + (size_t)32768 * G3;      // 32768*128 fp32 = 16.8 MB

    const dim3 gemmGrid(512, 6);

    gemm_gx<<<gemmGrid, 256, 0, stream>>>(x, w_ih0, b_ih, gxbuf, IN0);
    gru_scan<<<BATCH, 256, 0, stream>>>(gxbuf, w_hh, b_hh, hseq);

    for (int l = 1; l < NLAY; l++) {
        gemm_gx<<<gemmGrid, 256, 0, stream>>>(hseq,
                                              w_ih_rest + (size_t)(l - 1) * G3 * HID,
                                              b_ih + (size_t)l * G3,
                                              gxbuf, HID);
        gru_scan<<<BATCH, 256, 0, stream>>>(gxbuf,
                                            w_hh + (size_t)l * G3 * HID,
                                            b_hh + (size_t)l * G3,
                                            hseq);
    }

    fc_kernel<<<BATCH, 128, 0, stream>>>(hseq, fc_w, fc_b, out);
}

// Round 4
// 2795.399 us; speedup vs baseline: 1.0468x; 1.0468x over previous
//
#include <hip/hip_runtime.h>
#include <hip/hip_bf16.h>

// Problem constants
#define BATCH   64
#define SEQ     512
#define IN0     512
#define HID     128
#define G3      384   // 3*HID
#define NLAY    5

// ---------------------------------------------------------------------------
// gemm_gx: gx[M=32768][384] = A[M][K] @ W[384][K]^T + bias[384]   (all fp32)
// Tile 64(M) x 64(N), block 256 threads, 4x4 microtile, K-step 32.
// ---------------------------------------------------------------------------
__global__ __launch_bounds__(256) void gemm_gx(const float* __restrict__ A,
                                               const float* __restrict__ W,
                                               const float* __restrict__ bias,
                                               float* __restrict__ gx,
                                               int K)
{
    __shared__ __align__(16) float As[32][68];
    __shared__ __align__(16) float Bs[32][68];

    const int row0 = blockIdx.x * 64;
    const int col0 = blockIdx.y * 64;
    const int tid  = threadIdx.x;
    const int tx   = tid & 15;
    const int ty   = tid >> 4;
    const int r    = tid >> 2;
    const int kc   = (tid & 3) * 8;

    float acc[4][4] = {};

    for (int k0 = 0; k0 < K; k0 += 32) {
        {
            const float* Ap = A + (size_t)(row0 + r) * K + k0 + kc;
            float4 a0 = *(const float4*)(Ap);
            float4 a1 = *(const float4*)(Ap + 4);
            As[kc + 0][r] = a0.x; As[kc + 1][r] = a0.y; As[kc + 2][r] = a0.z; As[kc + 3][r] = a0.w;
            As[kc + 4][r] = a1.x; As[kc + 5][r] = a1.y; As[kc + 6][r] = a1.z; As[kc + 7][r] = a1.w;
        }
        {
            const float* Wp = W + (size_t)(col0 + r) * K + k0 + kc;
            float4 b0 = *(const float4*)(Wp);
            float4 b1 = *(const float4*)(Wp + 4);
            Bs[kc + 0][r] = b0.x; Bs[kc + 1][r] = b0.y; Bs[kc + 2][r] = b0.z; Bs[kc + 3][r] = b0.w;
            Bs[kc + 4][r] = b1.x; Bs[kc + 5][r] = b1.y; Bs[kc + 6][r] = b1.z; Bs[kc + 7][r] = b1.w;
        }
        __syncthreads();

        #pragma unroll
        for (int kk = 0; kk < 32; kk++) {
            float4 a = *(const float4*)&As[kk][ty * 4];
            float4 b = *(const float4*)&Bs[kk][tx * 4];
            acc[0][0] = fmaf(a.x, b.x, acc[0][0]); acc[0][1] = fmaf(a.x, b.y, acc[0][1]);
            acc[0][2] = fmaf(a.x, b.z, acc[0][2]); acc[0][3] = fmaf(a.x, b.w, acc[0][3]);
            acc[1][0] = fmaf(a.y, b.x, acc[1][0]); acc[1][1] = fmaf(a.y, b.y, acc[1][1]);
            acc[1][2] = fmaf(a.y, b.z, acc[1][2]); acc[1][3] = fmaf(a.y, b.w, acc[1][3]);
            acc[2][0] = fmaf(a.z, b.x, acc[2][0]); acc[2][1] = fmaf(a.z, b.y, acc[2][1]);
            acc[2][2] = fmaf(a.z, b.z, acc[2][2]); acc[2][3] = fmaf(a.z, b.w, acc[2][3]);
            acc[3][0] = fmaf(a.w, b.x, acc[3][0]); acc[3][1] = fmaf(a.w, b.y, acc[3][1]);
            acc[3][2] = fmaf(a.w, b.z, acc[3][2]); acc[3][3] = fmaf(a.w, b.w, acc[3][3]);
        }
        __syncthreads();
    }

    float bb[4];
    #pragma unroll
    for (int j = 0; j < 4; j++) bb[j] = bias[col0 + tx * 4 + j];
    #pragma unroll
    for (int i = 0; i < 4; i++) {
        const int row = row0 + ty * 4 + i;
        float4 v;
        v.x = acc[i][0] + bb[0];
        v.y = acc[i][1] + bb[1];
        v.z = acc[i][2] + bb[2];
        v.w = acc[i][3] + bb[3];
        *(float4*)&gx[(size_t)row * G3 + col0 + tx * 4] = v;
    }
}

// ---------------------------------------------------------------------------
// gru_scan v4: one block per batch element, 512 threads = 8 waves.
//   wave w = tid>>6:  q = w & 3 (k-quarter, wave-uniform!), half = w >> 2
//   lane ℓ:  jr = half*64 + ℓ  (matvec row base, rows {jr, jr+128, jr+256})
//            j0 = q*32 + (ℓ&31) (finalize index; lanes ℓ and ℓ+32 duplicate)
// Thread weights: rows {jr,+128,+256} x k-slice [32q,32q+32) = 96 VGPRs.
// h broadcast: lane ℓ holds h[32q+(ℓ&31)] in a register (vhs); matvec reads it
// via v_readlane (imm lane, wave-uniform k) on the VALU pipe — no LDS reads.
// Each wave redundantly finalizes its own 32-element h-slice, so h never
// round-trips through LDS: ONE barrier/step. LDS carries only the q-partials
// (double-buffered, q bank-swizzled -> conflict-free writes, b128 reads).
// gx prefetched one full step ahead (~850 cyc slack covers HBM latency).
// ---------------------------------------------------------------------------
__global__ __launch_bounds__(512, 2) void gru_scan(const float* __restrict__ gx,   // [BATCH][SEQ][384]
                                                   const float* __restrict__ w_hh, // [384][128] layer slice
                                                   const float* __restrict__ b_hh, // [384] layer slice
                                                   float* __restrict__ hseq)       // [BATCH][SEQ][128]
{
    const int b    = blockIdx.x;
    const int tid  = threadIdx.x;
    const int lane = tid & 63;
    const int w    = tid >> 6;
    const int q    = w & 3;        // wave-uniform k-quarter
    const int half = w >> 2;
    const int jr   = half * 64 + lane;      // [0,128)
    const int j0   = q * 32 + (lane & 31);  // finalize h index
    const int ko   = q * 32;

    // partials: [buf][gate][row][q(swizzled)] — 2*3*128*4*4B = 12 KB
    __shared__ __align__(16) float part[2][3][128][4];

    // ---- load this thread's 96 weights (3 rows x 32 k) into VGPRs ----
    float wr[32], wz[32], wn[32];
    {
        const float4* Wr = (const float4*)(w_hh + (size_t)(jr      ) * HID + ko);
        const float4* Wz = (const float4*)(w_hh + (size_t)(jr + 128) * HID + ko);
        const float4* Wn = (const float4*)(w_hh + (size_t)(jr + 256) * HID + ko);
        #pragma unroll
        for (int p = 0; p < 8; p++) {
            float4 f;
            f = Wr[p]; wr[4*p] = f.x; wr[4*p+1] = f.y; wr[4*p+2] = f.z; wr[4*p+3] = f.w;
            f = Wz[p]; wz[4*p] = f.x; wz[4*p+1] = f.y; wz[4*p+2] = f.z; wz[4*p+3] = f.w;
            f = Wn[p]; wn[4*p] = f.x; wn[4*p+1] = f.y; wn[4*p+2] = f.z; wn[4*p+3] = f.w;
        }
    }
    // finalize biases (per finalize index j0)
    const float bhr = b_hh[j0];
    const float bhz = b_hh[j0 + 128];
    const float bhn = b_hh[j0 + 256];

    const float* gxb  = gx   + (size_t)b * SEQ * G3;
    float*       hout = hseq + (size_t)b * SEQ * HID;
    const bool   st   = (half == 0) && (lane < 32);   // waves 0-3, lanes 0-31 cover all 128 j

    // preload gx for t=0
    float xr = gxb[j0];
    float xz = gxb[j0 + 128];
    float xn = gxb[j0 + 256];
    const float* gp = gxb + G3;

    const int qs = (q + (jr >> 3)) & 3;   // bank-swizzled q slot (write side only; sum is order-agnostic)

    float vhs = 0.f;   // lane-held h[j0]

    for (int t = 0; t < SEQ; t++) {
        // prefetch gx for t+1 (consumed after next barrier, > 1 step of slack)
        float nxr = 0.f, nxz = 0.f, nxn = 0.f;
        if (t + 1 < SEQ) { nxr = gp[j0]; nxz = gp[j0 + 128]; nxn = gp[j0 + 256]; }
        gp += G3;

        // matvec quarter-dots: h[32q+k] broadcast from lane k via readlane (VALU)
        float ar = 0.f, az = 0.f, an = 0.f;
        #pragma unroll
        for (int k = 0; k < 32; k++) {
            const float hk = __int_as_float(__builtin_amdgcn_readlane(__float_as_int(vhs), k));
            ar = fmaf(wr[k], hk, ar);
            az = fmaf(wz[k], hk, az);
            an = fmaf(wn[k], hk, an);
        }
        const int buf = t & 1;
        part[buf][0][jr][qs] = ar;
        part[buf][1][jr][qs] = az;
        part[buf][2][jr][qs] = an;
        __syncthreads();

        // redundant finalize for j0: sum 4 q-partials per gate (b128 reads)
        const float4 p0 = *(const float4*)part[buf][0][j0];
        const float4 p1 = *(const float4*)part[buf][1][j0];
        const float4 p2 = *(const float4*)part[buf][2][j0];
        const float ghr = ((p0.x + p0.y) + (p0.z + p0.w)) + bhr;
        const float ghz = ((p1.x + p1.y) + (p1.z + p1.w)) + bhz;
        const float ghn = ((p2.x + p2.y) + (p2.z + p2.w)) + bhn;

        const float rg  = 1.f / (1.f + __expf(-(xr + ghr)));
        const float zg  = 1.f / (1.f + __expf(-(xz + ghz)));
        const float pre = xn + rg * ghn;
        const float e   = __expf(-2.f * fabsf(pre));
        const float th  = copysignf((1.f - e) / (1.f + e), pre);   // tanh(pre)
        const float hnew = fmaf(zg, vhs - th, th);                 // (1-z)*n + z*h
        vhs = hnew;
        if (st) hout[(size_t)t * HID + j0] = hnew;

        xr = nxr; xz = nxz; xn = nxn;
    }
}

// ---------------------------------------------------------------------------
// fc: out[b][o] = hseq[b][T-1][:] . fc_w[o][:] + fc_b[o]
// ---------------------------------------------------------------------------
__global__ __launch_bounds__(128) void fc_kernel(const float* __restrict__ hseq,
                                                 const float* __restrict__ fc_w,
                                                 const float* __restrict__ fc_b,
                                                 float* __restrict__ out)
{
    const int b = blockIdx.x;
    const int o = threadIdx.x;
    if (o < 96) {
        const float* h = hseq + (size_t)b * (SEQ * HID) + (size_t)(SEQ - 1) * HID;
        const float* wrow = fc_w + o * HID;
        float acc = fc_b[o];
        #pragma unroll 4
        for (int k = 0; k < HID; k++) acc = fmaf(h[k], wrow[k], acc);
        out[b * 96 + o] = acc;
    }
}

// ---------------------------------------------------------------------------
extern "C" void kernel_launch(void* const* d_in, const int* in_sizes, int n_in,
                              void* d_out, int out_size, void* d_ws, size_t ws_size,
                              hipStream_t stream)
{
    const float* x         = (const float*)d_in[0]; // [64][512][512]
    const float* w_ih0     = (const float*)d_in[1]; // [384][512]
    const float* w_ih_rest = (const float*)d_in[2]; // [4][384][128]
    const float* w_hh      = (const float*)d_in[3]; // [5][384][128]
    const float* b_ih      = (const float*)d_in[4]; // [5][384]
    const float* b_hh      = (const float*)d_in[5]; // [5][384]
    const float* fc_w      = (const float*)d_in[6]; // [96][128]
    const float* fc_b      = (const float*)d_in[7]; // [96]
    float* out = (float*)d_out;                     // [64][96]

    float* gxbuf = (float*)d_ws;                    // 32768*384 fp32 = 50.3 MB
    float* hseq  = gxbuf + (size_t)32768 * G3;      // 32768*128 fp32 = 16.8 MB

    const dim3 gemmGrid(512, 6);

    gemm_gx<<<gemmGrid, 256, 0, stream>>>(x, w_ih0, b_ih, gxbuf, IN0);
    gru_scan<<<BATCH, 512, 0, stream>>>(gxbuf, w_hh, b_hh, hseq);

    for (int l = 1; l < NLAY; l++) {
        gemm_gx<<<gemmGrid, 256, 0, stream>>>(hseq,
                                              w_ih_rest + (size_t)(l - 1) * G3 * HID,
                                              b_ih + (size_t)l * G3,
                                              gxbuf, HID);
        gru_scan<<<BATCH, 512, 0, stream>>>(gxbuf,
                                            w_hh + (size_t)l * G3 * HID,
                                            b_hh + (size_t)l * G3,
                                            hseq);
    }

    fc_kernel<<<BATCH, 128, 0, stream>>>(hseq, fc_w, fc_b, out);
}